// Round 1
// baseline (804.757 us; speedup 1.0000x reference)
//
#include <hip/hip_runtime.h>
#include <math.h>

// entmax-bisect, alpha generic (fast path alpha=1.5 -> p(z)=z^2).
// One block per row. Row (d=32000) held in registers (64 f32/thread x 512 thr).
// Active set (X > max-1) compacted to LDS; 50 bisection iters on wave 0 only.

#define D_DIM   32000
#define NV4_TOT (D_DIM / 4)              // 8000 float4 per row
#define BLOCK   512
#define NWAVE   (BLOCK / 64)             // 8
#define KITER   ((NV4_TOT + BLOCK - 1) / BLOCK)   // 16
#define VPT     (4 * KITER)              // 64 elements per thread
#define CAP     8192                     // LDS active-list capacity (32 KB)
#define NITER   50

__device__ __forceinline__ float wave_sum(float v) {
#pragma unroll
    for (int off = 32; off > 0; off >>= 1) v += __shfl_xor(v, off, 64);
    return v;
}
__device__ __forceinline__ float wave_max(float v) {
#pragma unroll
    for (int off = 32; off > 0; off >>= 1) v = fmaxf(v, __shfl_xor(v, off, 64));
    return v;
}

__device__ __forceinline__ float pfun(float z, bool sq, float expo) {
    z = fmaxf(z, 0.0f);
    return sq ? z * z : powf(z, expo);
}

__global__ __launch_bounds__(BLOCK, 4)
void entmax_bisect_kernel(const float* __restrict__ x,
                          const float* __restrict__ alpha_p,
                          float* __restrict__ out) {
    const int row  = blockIdx.x;
    const int tid  = threadIdx.x;
    const int lane = tid & 63;
    const int wid  = tid >> 6;

    __shared__ float s_act[CAP];
    __shared__ float s_red[NWAVE];
    __shared__ float s_bcast[2];   // tau_final, sum_p
    __shared__ int   s_cnt;

    const float alpha = alpha_p[0];
    const float am1   = alpha - 1.0f;
    const float expo  = 1.0f / am1;
    const bool  sq    = (expo == 2.0f);   // alpha == 1.5 exact fast path

    const float4* __restrict__ x4 = (const float4*)(x + (size_t)row * D_DIM);
    float4* __restrict__ o4       = (float4*)(out + (size_t)row * D_DIM);

    // ---- Phase 1: load row into registers (X = x*am1), find max ----
    float X[VPT];
    float mx = -INFINITY;
#pragma unroll
    for (int k = 0; k < KITER; ++k) {
        const int i4 = tid + k * BLOCK;
        if (i4 < NV4_TOT) {
            float4 v = x4[i4];
            X[4 * k + 0] = v.x * am1;
            X[4 * k + 1] = v.y * am1;
            X[4 * k + 2] = v.z * am1;
            X[4 * k + 3] = v.w * am1;
        } else {
            X[4 * k + 0] = -INFINITY;
            X[4 * k + 1] = -INFINITY;
            X[4 * k + 2] = -INFINITY;
            X[4 * k + 3] = -INFINITY;
        }
    }
#pragma unroll
    for (int j = 0; j < VPT; ++j) mx = fmaxf(mx, X[j]);
    mx = wave_max(mx);
    if (lane == 0) s_red[wid] = mx;
    __syncthreads();
    float max_val = -INFINITY;
#pragma unroll
    for (int w = 0; w < NWAVE; ++w) max_val = fmaxf(max_val, s_red[w]);

    const float tau_lo0 = max_val - 1.0f;                       // max - gp(1)
    const float tau_hi  = max_val - powf(1.0f / (float)D_DIM, am1);
    const float dm0     = tau_hi - tau_lo0;

    // ---- Phase 2: compact active elements (X > tau_lo0) into LDS ----
    if (tid == 0) s_cnt = 0;
    __syncthreads();
#pragma unroll
    for (int j = 0; j < VPT; ++j) {
        if (X[j] > tau_lo0) {
            int p = atomicAdd(&s_cnt, 1);
            if (p < CAP) s_act[p] = X[j];
        }
    }
    __syncthreads();
    const int n_act = s_cnt;

    // ---- Phase 3: 50-step bisection ----
    if (n_act <= CAP) {
        // fast path: wave 0 only, shuffle reductions, no barriers in loop
        if (wid == 0) {
            float s = 0.0f;
            for (int i = lane; i < n_act; i += 64)
                s += pfun(s_act[i] - tau_lo0, sq, expo);
            s = wave_sum(s);
            const float f_lo = s - 1.0f;

            float tlo = tau_lo0, dm = dm0;
            float tau_m = tau_lo0, fsum = s;
            for (int it = 0; it < NITER; ++it) {
                dm *= 0.5f;
                tau_m = tlo + dm;
                float t = 0.0f;
                for (int i = lane; i < n_act; i += 64)
                    t += pfun(s_act[i] - tau_m, sq, expo);
                t = wave_sum(t);
                fsum = t;
                if ((t - 1.0f) * f_lo >= 0.0f) tlo = tau_m;
            }
            if (lane == 0) { s_bcast[0] = tau_m; s_bcast[1] = fsum; }
        }
        __syncthreads();
    } else {
        // fallback (never hit for N(0,1) inputs): full-block bisect over regs
        float s = 0.0f;
#pragma unroll
        for (int j = 0; j < VPT; ++j) s += pfun(X[j] - tau_lo0, sq, expo);
        s = wave_sum(s);
        if (lane == 0) s_red[wid] = s;
        __syncthreads();
        float tot = 0.0f;
#pragma unroll
        for (int w = 0; w < NWAVE; ++w) tot += s_red[w];
        const float f_lo = tot - 1.0f;

        float tlo = tau_lo0, dm = dm0;
        float tau_m = tau_lo0, fsum = tot;
        for (int it = 0; it < NITER; ++it) {
            dm *= 0.5f;
            tau_m = tlo + dm;
            float t = 0.0f;
#pragma unroll
            for (int j = 0; j < VPT; ++j) t += pfun(X[j] - tau_m, sq, expo);
            t = wave_sum(t);
            __syncthreads();           // protect s_red reuse
            if (lane == 0) s_red[wid] = t;
            __syncthreads();
            float tt = 0.0f;
#pragma unroll
            for (int w = 0; w < NWAVE; ++w) tt += s_red[w];
            fsum = tt;
            if ((tt - 1.0f) * f_lo >= 0.0f) tlo = tau_m;
        }
        if (tid == 0) { s_bcast[0] = tau_m; s_bcast[1] = fsum; }
        __syncthreads();
    }

    // ---- Phase 4: write p(X - tau_final) / sum ----
    const float tau_f = s_bcast[0];
    const float invS  = 1.0f / s_bcast[1];
#pragma unroll
    for (int k = 0; k < KITER; ++k) {
        const int i4 = tid + k * BLOCK;
        if (i4 < NV4_TOT) {
            float4 o;
            o.x = pfun(X[4 * k + 0] - tau_f, sq, expo) * invS;
            o.y = pfun(X[4 * k + 1] - tau_f, sq, expo) * invS;
            o.z = pfun(X[4 * k + 2] - tau_f, sq, expo) * invS;
            o.w = pfun(X[4 * k + 3] - tau_f, sq, expo) * invS;
            o4[i4] = o;
        }
    }
}

extern "C" void kernel_launch(void* const* d_in, const int* in_sizes, int n_in,
                              void* d_out, int out_size, void* d_ws, size_t ws_size,
                              hipStream_t stream) {
    const float* x       = (const float*)d_in[0];
    const float* alpha_p = (const float*)d_in[1];
    float* out           = (float*)d_out;
    const int rows       = in_sizes[0] / D_DIM;   // 2048
    entmax_bisect_kernel<<<rows, BLOCK, 0, stream>>>(x, alpha_p, out);
}

// Round 2
// 529.825 us; speedup vs baseline: 1.5189x; 1.5189x over previous
//
#include <hip/hip_runtime.h>
#include <math.h>

// alpha-entmax via bisection (reference: entmax.EntmaxBisect, 50 iters).
// Key facts exploited:
//  * tau >= max-1 for every iterate, so elements with X <= max-1 contribute 0
//    always and output exactly 0. For N(0,1)/alpha=1.5 that's ~98% of the row.
//  * For alpha=1.5 (bench case) f(tau)=sum max(X-tau,0)^2 - 1 is convex
//    decreasing; Newton from tau_lo converges monotonically from the left
//    (tangent below convex fn => never overshoots) to fp32 machine eps,
//    matching the 50-step bisection to ~1e-5 (threshold 1.8e-2).
// Structure: 1 block/row. Pass1 max; Pass2 re-read (L3-hot) + compact actives
// (val + u16 idx) to LDS + zero-fill out; wave-0 Newton; scatter actives.
// No per-thread row cache => no scratch spills (R1 failure mode: VGPR=64 with
// X[64] array => spills, WRITE_SIZE 448MB vs 262 ideal).

#define D_DIM   32000
#define NV4     (D_DIM / 4)          // 8000 float4 per row
#define BLOCK   512
#define NWAVE   (BLOCK / 64)         // 8
#define CAP     4096                 // LDS active-list capacity (~6x typical)
#define NEWTON  26
#define NITER   50

__device__ __forceinline__ float wave_max(float v) {
#pragma unroll
    for (int off = 32; off > 0; off >>= 1) v = fmaxf(v, __shfl_xor(v, off, 64));
    return v;
}
__device__ __forceinline__ float wave_sum(float v) {
#pragma unroll
    for (int off = 32; off > 0; off >>= 1) v += __shfl_xor(v, off, 64);
    return v;
}
__device__ __forceinline__ float pf(float z, bool sq, float expo) {
    z = fmaxf(z, 0.0f);
    return sq ? z * z : powf(z, expo);
}

__global__ __launch_bounds__(BLOCK, 8)   // cap VGPR at 64 -> 4 blocks/CU
void entmax_bisect_kernel(const float* __restrict__ x,
                          const float* __restrict__ alpha_p,
                          float* __restrict__ out) {
    const int row  = blockIdx.x;
    const int tid  = threadIdx.x;
    const int lane = tid & 63;
    const int wid  = tid >> 6;

    __shared__ float          s_val[CAP];   // 16 KB
    __shared__ unsigned short s_idx[CAP];   //  8 KB
    __shared__ float          s_red[NWAVE];
    __shared__ float          s_bc[2];      // tau_final, sum_p
    __shared__ int            s_cnt;

    const float alpha = alpha_p[0];
    const float am1   = alpha - 1.0f;
    const float expo  = 1.0f / am1;
    const bool  sq    = (expo == 2.0f);     // alpha == 1.5 exact fast path

    const float4* __restrict__ x4 = (const float4*)(x + (size_t)row * D_DIM);
    float4*       __restrict__ o4 = (float4*)(out + (size_t)row * D_DIM);

    // ---- Pass 1: row max of X = x*am1 (multiply-then-max matches ref rounding)
    float mx = -INFINITY;
    for (int i4 = tid; i4 < NV4; i4 += BLOCK) {
        float4 v = x4[i4];
        mx = fmaxf(mx, fmaxf(fmaxf(v.x * am1, v.y * am1),
                             fmaxf(v.z * am1, v.w * am1)));
    }
    mx = wave_max(mx);
    if (lane == 0) s_red[wid] = mx;
    if (tid == 0) s_cnt = 0;
    __syncthreads();
    float max_val = s_red[0];
#pragma unroll
    for (int w = 1; w < NWAVE; ++w) max_val = fmaxf(max_val, s_red[w]);

    const float tau_lo0 = max_val - 1.0f;

    // ---- Pass 2: compact actives into LDS (ballot-aggregated), zero-fill out
    const float4 zero4 = make_float4(0.f, 0.f, 0.f, 0.f);
    for (int i4 = tid; i4 < NV4; i4 += BLOCK) {
        float4 v = x4[i4];
        float Xc[4] = {v.x * am1, v.y * am1, v.z * am1, v.w * am1};
        o4[i4] = zero4;
#pragma unroll
        for (int c = 0; c < 4; ++c) {
            const bool on = Xc[c] > tau_lo0;
            const unsigned long long m = __ballot(on);
            if (m) {
                const int leader = (int)__ffsll(m) - 1;
                int base = 0;
                if (lane == leader) base = atomicAdd(&s_cnt, (int)__popcll(m));
                base = __shfl(base, leader, 64);
                if (on) {
                    const int pos = base +
                        (int)__popcll(m & ((1ull << lane) - 1ull));
                    if (pos < CAP) {
                        s_val[pos] = Xc[c];
                        s_idx[pos] = (unsigned short)(i4 * 4 + c);
                    }
                }
            }
        }
    }
    __syncthreads();
    const int n_act = s_cnt;

    if (n_act <= CAP) {
        // ---- Solve on wave 0 (others park at the barrier; zero stores drain)
        if (wid == 0) {
            float tau, S;
            if (sq) {
                // monotone Newton on f(tau) = sum z^2 - 1 (convex, decreasing)
                tau = tau_lo0;
                for (int it = 0; it < NEWTON; ++it) {
                    float s1 = 0.f, s2 = 0.f;
                    for (int i = lane; i < n_act; i += 64) {
                        const float z = fmaxf(s_val[i] - tau, 0.f);
                        s1 += z; s2 += z * z;
                    }
#pragma unroll
                    for (int off = 32; off > 0; off >>= 1) { // joint reduce
                        s1 += __shfl_xor(s1, off, 64);
                        s2 += __shfl_xor(s2, off, 64);
                    }
                    tau += (s2 - 1.0f) / fmaxf(2.0f * s1, 1e-30f);
                }
                float s2 = 0.f;
                for (int i = lane; i < n_act; i += 64) {
                    const float z = fmaxf(s_val[i] - tau, 0.f);
                    s2 += z * z;
                }
                S = wave_sum(s2);
            } else {
                // generic alpha: faithful 50-step bisection over actives
                const float tau_hi = max_val - powf(1.0f / (float)D_DIM, am1);
                float dm = tau_hi - tau_lo0;
                float s = 0.f;
                for (int i = lane; i < n_act; i += 64)
                    s += pf(s_val[i] - tau_lo0, sq, expo);
                s = wave_sum(s);
                const float f_lo = s - 1.0f;
                float tlo = tau_lo0, tau_m = tau_lo0, fsum = s;
                for (int it = 0; it < NITER; ++it) {
                    dm *= 0.5f;
                    tau_m = tlo + dm;
                    float t = 0.f;
                    for (int i = lane; i < n_act; i += 64)
                        t += pf(s_val[i] - tau_m, sq, expo);
                    t = wave_sum(t);
                    fsum = t;
                    if ((t - 1.0f) * f_lo >= 0.0f) tlo = tau_m;
                }
                tau = tau_m; S = fsum;
            }
            if (lane == 0) { s_bc[0] = tau; s_bc[1] = S; }
        }
        __syncthreads();   // drains pass-2 zero stores (vmcnt(0)) + publishes tau

        // ---- Scatter nonzero outputs
        const float tau_f = s_bc[0];
        const float invS  = 1.0f / s_bc[1];
        for (int i = tid; i < n_act; i += BLOCK) {
            const float z = fmaxf(s_val[i] - tau_f, 0.f);
            const float p = sq ? z * z : powf(z, expo);
            out[(size_t)row * D_DIM + s_idx[i]] = p * invS;
        }
    } else {
        // ---- Overflow fallback (pathological inputs only): full-block
        //      50-step bisection re-reading x from global each iteration.
        const float tau_hi = max_val - powf(1.0f / (float)D_DIM, am1);
        float dm = tau_hi - tau_lo0;
        float s = 0.f;
        for (int i4 = tid; i4 < NV4; i4 += BLOCK) {
            float4 v = x4[i4];
            s += pf(v.x * am1 - tau_lo0, sq, expo) + pf(v.y * am1 - tau_lo0, sq, expo)
               + pf(v.z * am1 - tau_lo0, sq, expo) + pf(v.w * am1 - tau_lo0, sq, expo);
        }
        s = wave_sum(s);
        __syncthreads();
        if (lane == 0) s_red[wid] = s;
        __syncthreads();
        float tot = 0.f;
#pragma unroll
        for (int w = 0; w < NWAVE; ++w) tot += s_red[w];
        const float f_lo = tot - 1.0f;
        float tlo = tau_lo0, tau_m = tau_lo0, fsum = tot;
        for (int it = 0; it < NITER; ++it) {
            dm *= 0.5f;
            tau_m = tlo + dm;
            float t = 0.f;
            for (int i4 = tid; i4 < NV4; i4 += BLOCK) {
                float4 v = x4[i4];
                t += pf(v.x * am1 - tau_m, sq, expo) + pf(v.y * am1 - tau_m, sq, expo)
                   + pf(v.z * am1 - tau_m, sq, expo) + pf(v.w * am1 - tau_m, sq, expo);
            }
            t = wave_sum(t);
            __syncthreads();
            if (lane == 0) s_red[wid] = t;
            __syncthreads();
            float tt = 0.f;
#pragma unroll
            for (int w = 0; w < NWAVE; ++w) tt += s_red[w];
            fsum = tt;
            if ((tt - 1.0f) * f_lo >= 0.0f) tlo = tau_m;
        }
        const float invS = 1.0f / fsum;
        __syncthreads();   // drain zero-fill stores before overwrite
        for (int i4 = tid; i4 < NV4; i4 += BLOCK) {
            float4 v = x4[i4];
            float4 o;
            o.x = pf(v.x * am1 - tau_m, sq, expo) * invS;
            o.y = pf(v.y * am1 - tau_m, sq, expo) * invS;
            o.z = pf(v.z * am1 - tau_m, sq, expo) * invS;
            o.w = pf(v.w * am1 - tau_m, sq, expo) * invS;
            o4[i4] = o;
        }
    }
}

extern "C" void kernel_launch(void* const* d_in, const int* in_sizes, int n_in,
                              void* d_out, int out_size, void* d_ws, size_t ws_size,
                              hipStream_t stream) {
    const float* x       = (const float*)d_in[0];
    const float* alpha_p = (const float*)d_in[1];
    float* out           = (float*)d_out;
    const int rows       = in_sizes[0] / D_DIM;   // 2048
    entmax_bisect_kernel<<<rows, BLOCK, 0, stream>>>(x, alpha_p, out);
}

// Round 3
// 488.829 us; speedup vs baseline: 1.6463x; 1.0839x over previous
//
#include <hip/hip_runtime.h>
#include <math.h>

// alpha-entmax via bisection (ref: entmax.EntmaxBisect, 50 iters), fused
// single-pass version.
//
// Facts exploited:
//  * Every bisection iterate tau >= gmax-1, so elements with X <= gmax-1
//    contribute 0 to all sums and output exactly 0 (~98% of row for this data).
//  * Candidate filter only needs a threshold <= gmax-1: a monotone block-shared
//    RUNNING max works. Extra candidates (X <= gmax-1) contribute 0 to the
//    solve and scatter p=0 onto an already-zeroed output -> harmless.
//  * alpha=1.5: f(tau)=sum max(X-tau,0)^2-1 is convex decreasing; Newton from
//    tau_lo converges monotonically (tangent below convex fn), ~8 iters to
//    fp32 eps; early-exit on step size.
// Structure: 1 block/row, ONE streaming pass (read x + zero-fill out +
// running-max + deferred candidate append via per-thread LDS atomicAdd),
// wave-0 Newton, scatter actives. R2's ballot-leader-shfl compaction and the
// separate max pass are gone (they were the dominant instruction stream:
// VALUBusy 19%, HBM only 38% of achievable).

#define D_DIM   32000
#define NV4     (D_DIM / 4)          // 8000 float4 per row
#define BLOCK   512
#define NWAVE   (BLOCK / 64)         // 8
#define CAP     6144                 // candidate capacity (val+u16 idx = 36 KB)
#define NEWTON_MAX 30
#define NITER   50

__device__ __forceinline__ float wave_sum(float v) {
#pragma unroll
    for (int off = 32; off > 0; off >>= 1) v += __shfl_xor(v, off, 64);
    return v;
}
__device__ __forceinline__ float pf(float z, bool sq, float expo) {
    z = fmaxf(z, 0.0f);
    return sq ? z * z : powf(z, expo);
}
// order-preserving float<->uint maps (for LDS atomicMax running max)
__device__ __forceinline__ unsigned fflip(float f) {
    unsigned u = __float_as_uint(f);
    return u ^ ((u >> 31) ? 0xFFFFFFFFu : 0x80000000u);
}
__device__ __forceinline__ float funflip(unsigned u) {
    return __uint_as_float(u ^ ((u & 0x80000000u) ? 0x80000000u : 0xFFFFFFFFu));
}

__global__ __launch_bounds__(BLOCK, 8)
void entmax_bisect_kernel(const float* __restrict__ x,
                          const float* __restrict__ alpha_p,
                          float* __restrict__ out) {
    const int row  = blockIdx.x;
    const int tid  = threadIdx.x;
    const int lane = tid & 63;
    const int wid  = tid >> 6;

    __shared__ float          s_val[CAP];    // 24 KB
    __shared__ unsigned short s_idx[CAP];    // 12 KB
    __shared__ float          s_red[NWAVE];
    __shared__ float          s_bc[2];       // tau_final, sum_p
    __shared__ int            s_cnt;
    volatile __shared__ unsigned s_gmax;     // running max, fflip domain

    const float alpha = alpha_p[0];
    const float am1   = alpha - 1.0f;
    const float expo  = 1.0f / am1;
    const bool  sq    = (expo == 2.0f);      // alpha == 1.5 exact fast path

    const float4* __restrict__ x4 = (const float4*)(x + (size_t)row * D_DIM);
    float4*       __restrict__ o4 = (float4*)(out + (size_t)row * D_DIM);

    if (tid == 0) { s_cnt = 0; s_gmax = 0u; }   // 0u < fflip(-inf)
    __syncthreads();

    // ---- Single streaming pass: zero-fill out, running max, deferred append
    const float4 zero4 = make_float4(0.f, 0.f, 0.f, 0.f);
    float  pX[4];
    int    pI4 = -1;                    // previous chunk pending append
    for (int i4 = tid; i4 < NV4; i4 += BLOCK) {
        float4 v = x4[i4];
        o4[i4] = zero4;
        float X0 = v.x * am1, X1 = v.y * am1, X2 = v.z * am1, X3 = v.w * am1;
        const float m4 = fmaxf(fmaxf(X0, X1), fmaxf(X2, X3));
        const unsigned fm = fflip(m4);
        if (fm > s_gmax) atomicMax((unsigned*)&s_gmax, fm);
        // append PREVIOUS chunk's candidates with the improved threshold
        if (pI4 >= 0) {
            const float thr = funflip(s_gmax) - 1.0f;
            const bool o0 = pX[0] > thr, o1 = pX[1] > thr,
                       o2 = pX[2] > thr, o3 = pX[3] > thr;
            const int cnt = (int)o0 + (int)o1 + (int)o2 + (int)o3;
            if (cnt) {
                int base = atomicAdd(&s_cnt, cnt);
                const int bidx = pI4 * 4;
#pragma unroll
                for (int c = 0; c < 4; ++c) {
                    const bool on = (c == 0) ? o0 : (c == 1) ? o1 : (c == 2) ? o2 : o3;
                    if (on) {
                        if (base < CAP) {
                            s_val[base] = pX[c];
                            s_idx[base] = (unsigned short)(bidx + c);
                        }
                        ++base;
                    }
                }
            }
        }
        pX[0] = X0; pX[1] = X1; pX[2] = X2; pX[3] = X3; pI4 = i4;
    }
    // flush last chunk
    if (pI4 >= 0) {
        const float thr = funflip(s_gmax) - 1.0f;
        const bool o0 = pX[0] > thr, o1 = pX[1] > thr,
                   o2 = pX[2] > thr, o3 = pX[3] > thr;
        const int cnt = (int)o0 + (int)o1 + (int)o2 + (int)o3;
        if (cnt) {
            int base = atomicAdd(&s_cnt, cnt);
            const int bidx = pI4 * 4;
#pragma unroll
            for (int c = 0; c < 4; ++c) {
                const bool on = (c == 0) ? o0 : (c == 1) ? o1 : (c == 2) ? o2 : o3;
                if (on) {
                    if (base < CAP) {
                        s_val[base] = pX[c];
                        s_idx[base] = (unsigned short)(bidx + c);
                    }
                    ++base;
                }
            }
        }
    }
    __syncthreads();
    const int   n_act   = s_cnt;
    const float max_val = funflip(s_gmax);   // exact global max after barrier
    const float tau_lo0 = max_val - 1.0f;

    if (n_act <= CAP) {
        // ---- Solve on wave 0 (candidate list; extras contribute exactly 0)
        if (wid == 0) {
            float tau, S;
            if (sq) {
                // monotone Newton with early exit
                tau = tau_lo0;
                for (int it = 0; it < NEWTON_MAX; ++it) {
                    float s1 = 0.f, s2 = 0.f;
                    for (int i = lane; i < n_act; i += 64) {
                        const float z = fmaxf(s_val[i] - tau, 0.f);
                        s1 += z; s2 += z * z;
                    }
#pragma unroll
                    for (int off = 32; off > 0; off >>= 1) {
                        s1 += __shfl_xor(s1, off, 64);
                        s2 += __shfl_xor(s2, off, 64);
                    }
                    const float dtau = (s2 - 1.0f) / fmaxf(2.0f * s1, 1e-30f);
                    tau += dtau;
                    if (dtau < 1e-7f * fmaxf(1.0f, fabsf(tau))) break;
                }
                float s2 = 0.f;
                for (int i = lane; i < n_act; i += 64) {
                    const float z = fmaxf(s_val[i] - tau, 0.f);
                    s2 += z * z;
                }
                S = wave_sum(s2);
            } else {
                // generic alpha: faithful 50-step bisection over candidates
                const float tau_hi = max_val - powf(1.0f / (float)D_DIM, am1);
                float dm = tau_hi - tau_lo0;
                float s = 0.f;
                for (int i = lane; i < n_act; i += 64)
                    s += pf(s_val[i] - tau_lo0, sq, expo);
                s = wave_sum(s);
                const float f_lo = s - 1.0f;
                float tlo = tau_lo0, tau_m = tau_lo0, fsum = s;
                for (int it = 0; it < NITER; ++it) {
                    dm *= 0.5f;
                    tau_m = tlo + dm;
                    float t = 0.f;
                    for (int i = lane; i < n_act; i += 64)
                        t += pf(s_val[i] - tau_m, sq, expo);
                    t = wave_sum(t);
                    fsum = t;
                    if ((t - 1.0f) * f_lo >= 0.0f) tlo = tau_m;
                }
                tau = tau_m; S = fsum;
            }
            if (lane == 0) { s_bc[0] = tau; s_bc[1] = S; }
        }
        __syncthreads();   // drains zero stores (vmcnt(0)) + publishes tau

        // ---- Scatter nonzero outputs
        const float tau_f = s_bc[0];
        const float invS  = 1.0f / s_bc[1];
        for (int i = tid; i < n_act; i += BLOCK) {
            const float z = fmaxf(s_val[i] - tau_f, 0.f);
            const float p = sq ? z * z : powf(z, expo);
            out[(size_t)row * D_DIM + s_idx[i]] = p * invS;
        }
    } else {
        // ---- Overflow fallback (never hit for bench data): full-row
        //      50-step bisection re-reading x from global each iteration.
        const float tau_hi = max_val - powf(1.0f / (float)D_DIM, am1);
        float dm = tau_hi - tau_lo0;
        float s = 0.f;
        for (int i4 = tid; i4 < NV4; i4 += BLOCK) {
            float4 v = x4[i4];
            s += pf(v.x * am1 - tau_lo0, sq, expo) + pf(v.y * am1 - tau_lo0, sq, expo)
               + pf(v.z * am1 - tau_lo0, sq, expo) + pf(v.w * am1 - tau_lo0, sq, expo);
        }
        s = wave_sum(s);
        __syncthreads();
        if (lane == 0) s_red[wid] = s;
        __syncthreads();
        float tot = 0.f;
#pragma unroll
        for (int w = 0; w < NWAVE; ++w) tot += s_red[w];
        const float f_lo = tot - 1.0f;
        float tlo = tau_lo0, tau_m = tau_lo0, fsum = tot;
        for (int it = 0; it < NITER; ++it) {
            dm *= 0.5f;
            tau_m = tlo + dm;
            float t = 0.f;
            for (int i4 = tid; i4 < NV4; i4 += BLOCK) {
                float4 v = x4[i4];
                t += pf(v.x * am1 - tau_m, sq, expo) + pf(v.y * am1 - tau_m, sq, expo)
                   + pf(v.z * am1 - tau_m, sq, expo) + pf(v.w * am1 - tau_m, sq, expo);
            }
            t = wave_sum(t);
            __syncthreads();
            if (lane == 0) s_red[wid] = t;
            __syncthreads();
            float tt = 0.f;
#pragma unroll
            for (int w = 0; w < NWAVE; ++w) tt += s_red[w];
            fsum = tt;
            if ((tt - 1.0f) * f_lo >= 0.0f) tlo = tau_m;
        }
        const float invS = 1.0f / fsum;
        __syncthreads();   // drain zero-fill stores before overwrite
        for (int i4 = tid; i4 < NV4; i4 += BLOCK) {
            float4 v = x4[i4];
            float4 o;
            o.x = pf(v.x * am1 - tau_m, sq, expo) * invS;
            o.y = pf(v.y * am1 - tau_m, sq, expo) * invS;
            o.z = pf(v.z * am1 - tau_m, sq, expo) * invS;
            o.w = pf(v.w * am1 - tau_m, sq, expo) * invS;
            o4[i4] = o;
        }
    }
}

extern "C" void kernel_launch(void* const* d_in, const int* in_sizes, int n_in,
                              void* d_out, int out_size, void* d_ws, size_t ws_size,
                              hipStream_t stream) {
    const float* x       = (const float*)d_in[0];
    const float* alpha_p = (const float*)d_in[1];
    float* out           = (float*)d_out;
    const int rows       = in_sizes[0] / D_DIM;   // 2048
    entmax_bisect_kernel<<<rows, BLOCK, 0, stream>>>(x, alpha_p, out);
}

// Round 4
// 481.781 us; speedup vs baseline: 1.6704x; 1.0146x over previous
//
#include <hip/hip_runtime.h>
#include <math.h>

// alpha-entmax via bisection (ref: entmax.EntmaxBisect, 50 iters).
// Single fused streaming pass, GROUP=4 software-pipelined.
//
// Facts exploited:
//  * Every bisection iterate tau >= gmax-1, so elements with X <= gmax-1
//    contribute 0 to all sums and output exactly 0 (~98% of row here).
//  * Candidate filter only needs a threshold <= gmax-1: a monotone running
//    max works; extra candidates contribute 0 to the solve and scatter p=0
//    onto already-zeroed output -> harmless.
//  * alpha=1.5: f(tau)=sum max(X-tau,0)^2-1 convex decreasing; Newton from
//    tau_lo converges monotonically, ~8-12 iters to fp32 eps (early exit).
// R3 post-mortem: per-chunk volatile LDS reads + atomics serialized the
// global-load chain (~1 outstanding load/wave, 2.4 TB/s plateau, VALU 23%).
// R4: 4-chunk groups -> 4 loads+4 stores in flight, ONE LDS RT per group,
// deferred-by-one-group candidate append.

#define D_DIM   32000
#define NV4     (D_DIM / 4)          // 8000 float4 per row
#define BLOCK   512
#define NWAVE   (BLOCK / 64)         // 8
#define GROUP   4                    // chunks per prefetch group
#define CAP     6144                 // candidate capacity (val+u16 idx = 36 KB)
#define NEWTON_MAX 30
#define NITER   50

__device__ __forceinline__ float wave_sum(float v) {
#pragma unroll
    for (int off = 32; off > 0; off >>= 1) v += __shfl_xor(v, off, 64);
    return v;
}
__device__ __forceinline__ float pf(float z, bool sq, float expo) {
    z = fmaxf(z, 0.0f);
    return sq ? z * z : powf(z, expo);
}
// order-preserving float<->uint maps (for LDS atomicMax running max)
__device__ __forceinline__ unsigned fflip(float f) {
    unsigned u = __float_as_uint(f);
    return u ^ ((u >> 31) ? 0xFFFFFFFFu : 0x80000000u);
}
__device__ __forceinline__ float funflip(unsigned u) {
    return __uint_as_float(u ^ ((u & 0x80000000u) ? 0x80000000u : 0xFFFFFFFFu));
}

__global__ __launch_bounds__(BLOCK, 4)   // VGPR cap 128 (prefetch needs ~75)
void entmax_bisect_kernel(const float* __restrict__ x,
                          const float* __restrict__ alpha_p,
                          float* __restrict__ out) {
    const int row  = blockIdx.x;
    const int tid  = threadIdx.x;
    const int lane = tid & 63;
    const int wid  = tid >> 6;

    __shared__ float          s_val[CAP];    // 24 KB
    __shared__ unsigned short s_idx[CAP];    // 12 KB
    __shared__ float          s_red[NWAVE];
    __shared__ float          s_bc[2];       // tau_final, sum_p
    __shared__ int            s_cnt;
    volatile __shared__ unsigned s_gmax;     // running max, fflip domain

    const float alpha = alpha_p[0];
    const float am1   = alpha - 1.0f;
    const float expo  = 1.0f / am1;
    const bool  sq    = (expo == 2.0f);      // alpha == 1.5 exact fast path

    const float4* __restrict__ x4 = (const float4*)(x + (size_t)row * D_DIM);
    float4*       __restrict__ o4 = (float4*)(out + (size_t)row * D_DIM);

    if (tid == 0) { s_cnt = 0; s_gmax = 0u; }   // 0u < fflip(any float)
    __syncthreads();

    // ---- Single streaming pass, GROUP-wise pipelined ----
    const float4 zero4 = make_float4(0.f, 0.f, 0.f, 0.f);
    float Xp[GROUP][4];
    int   pG0 = -1;                    // previous group's base chunk index

    for (int g0 = tid; g0 < NV4; g0 += GROUP * BLOCK) {   // 4 iterations
        // 1) issue all GROUP loads + zero-stores (independent, stay in flight)
        float4 v[GROUP];
#pragma unroll
        for (int u = 0; u < GROUP; ++u) {
            const int i4 = g0 + u * BLOCK;
            if (i4 < NV4) {
                v[u] = x4[i4];
                o4[i4] = zero4;
            } else {
                v[u] = make_float4(-INFINITY, -INFINITY, -INFINITY, -INFINITY);
            }
        }
        // 2) X = x*am1, group max
        float X[GROUP][4];
        float gm = -INFINITY;
#pragma unroll
        for (int u = 0; u < GROUP; ++u) {
            X[u][0] = v[u].x * am1; X[u][1] = v[u].y * am1;
            X[u][2] = v[u].z * am1; X[u][3] = v[u].w * am1;
            gm = fmaxf(gm, fmaxf(fmaxf(X[u][0], X[u][1]),
                                 fmaxf(X[u][2], X[u][3])));
        }
        // 3) ONE LDS round trip: read running max, publish ours if larger
        unsigned r = s_gmax;
        const unsigned fm = fflip(gm);
        if (fm > r) { atomicMax((unsigned*)&s_gmax, fm); r = fm; }
        // 4) append PREVIOUS group's candidates (threshold now includes all
        //    of that group's atomics from every thread that reached step 3)
        if (pG0 >= 0) {
            const float thr = funflip(r) - 1.0f;
            int cnt = 0;
            bool on[GROUP][4];
#pragma unroll
            for (int u = 0; u < GROUP; ++u)
#pragma unroll
                for (int c = 0; c < 4; ++c) {
                    on[u][c] = Xp[u][c] > thr;
                    cnt += (int)on[u][c];
                }
            if (cnt) {
                int base = atomicAdd(&s_cnt, cnt);
#pragma unroll
                for (int u = 0; u < GROUP; ++u)
#pragma unroll
                    for (int c = 0; c < 4; ++c)
                        if (on[u][c]) {
                            if (base < CAP) {
                                s_val[base] = Xp[u][c];
                                s_idx[base] = (unsigned short)((pG0 + u * BLOCK) * 4 + c);
                            }
                            ++base;
                        }
            }
        }
        // 5) rotate
#pragma unroll
        for (int u = 0; u < GROUP; ++u)
#pragma unroll
            for (int c = 0; c < 4; ++c) Xp[u][c] = X[u][c];
        pG0 = g0;
    }
    // flush last group (X = -inf for invalid chunks self-guards the compare)
    if (pG0 >= 0) {
        const float thr = funflip((unsigned)s_gmax) - 1.0f;
        int cnt = 0;
        bool on[GROUP][4];
#pragma unroll
        for (int u = 0; u < GROUP; ++u)
#pragma unroll
            for (int c = 0; c < 4; ++c) {
                on[u][c] = Xp[u][c] > thr;
                cnt += (int)on[u][c];
            }
        if (cnt) {
            int base = atomicAdd(&s_cnt, cnt);
#pragma unroll
            for (int u = 0; u < GROUP; ++u)
#pragma unroll
                for (int c = 0; c < 4; ++c)
                    if (on[u][c]) {
                        if (base < CAP) {
                            s_val[base] = Xp[u][c];
                            s_idx[base] = (unsigned short)((pG0 + u * BLOCK) * 4 + c);
                        }
                        ++base;
                    }
        }
    }
    __syncthreads();
    const int   n_act   = s_cnt;
    const float max_val = funflip((unsigned)s_gmax);  // exact global max now
    const float tau_lo0 = max_val - 1.0f;

    if (n_act <= CAP) {
        // ---- Solve on wave 0 (extras in candidate list contribute exactly 0)
        if (wid == 0) {
            float tau, S;
            if (sq) {
                tau = tau_lo0;                      // monotone Newton
                for (int it = 0; it < NEWTON_MAX; ++it) {
                    float s1 = 0.f, s2 = 0.f;
                    for (int i = lane; i < n_act; i += 64) {
                        const float z = fmaxf(s_val[i] - tau, 0.f);
                        s1 += z; s2 += z * z;
                    }
#pragma unroll
                    for (int off = 32; off > 0; off >>= 1) {
                        s1 += __shfl_xor(s1, off, 64);
                        s2 += __shfl_xor(s2, off, 64);
                    }
                    const float dtau = (s2 - 1.0f) / fmaxf(2.0f * s1, 1e-30f);
                    tau += dtau;
                    if (dtau < 1e-7f * fmaxf(1.0f, fabsf(tau))) break;
                }
                float s2 = 0.f;
                for (int i = lane; i < n_act; i += 64) {
                    const float z = fmaxf(s_val[i] - tau, 0.f);
                    s2 += z * z;
                }
                S = wave_sum(s2);
            } else {
                // generic alpha: faithful 50-step bisection over candidates
                const float tau_hi = max_val - powf(1.0f / (float)D_DIM, am1);
                float dm = tau_hi - tau_lo0;
                float s = 0.f;
                for (int i = lane; i < n_act; i += 64)
                    s += pf(s_val[i] - tau_lo0, sq, expo);
                s = wave_sum(s);
                const float f_lo = s - 1.0f;
                float tlo = tau_lo0, tau_m = tau_lo0, fsum = s;
                for (int it = 0; it < NITER; ++it) {
                    dm *= 0.5f;
                    tau_m = tlo + dm;
                    float t = 0.f;
                    for (int i = lane; i < n_act; i += 64)
                        t += pf(s_val[i] - tau_m, sq, expo);
                    t = wave_sum(t);
                    fsum = t;
                    if ((t - 1.0f) * f_lo >= 0.0f) tlo = tau_m;
                }
                tau = tau_m; S = fsum;
            }
            if (lane == 0) { s_bc[0] = tau; s_bc[1] = S; }
        }
        __syncthreads();   // drains zero stores (vmcnt(0)) + publishes tau

        // ---- Scatter nonzero outputs
        const float tau_f = s_bc[0];
        const float invS  = 1.0f / s_bc[1];
        for (int i = tid; i < n_act; i += BLOCK) {
            const float z = fmaxf(s_val[i] - tau_f, 0.f);
            const float p = sq ? z * z : powf(z, expo);
            out[(size_t)row * D_DIM + s_idx[i]] = p * invS;
        }
    } else {
        // ---- Overflow fallback (pathological inputs only): full-row
        //      50-step bisection re-reading x from global each iteration.
        const float tau_hi = max_val - powf(1.0f / (float)D_DIM, am1);
        float dm = tau_hi - tau_lo0;
        float s = 0.f;
        for (int i4 = tid; i4 < NV4; i4 += BLOCK) {
            float4 v = x4[i4];
            s += pf(v.x * am1 - tau_lo0, sq, expo) + pf(v.y * am1 - tau_lo0, sq, expo)
               + pf(v.z * am1 - tau_lo0, sq, expo) + pf(v.w * am1 - tau_lo0, sq, expo);
        }
        s = wave_sum(s);
        __syncthreads();
        if (lane == 0) s_red[wid] = s;
        __syncthreads();
        float tot = 0.f;
#pragma unroll
        for (int w = 0; w < NWAVE; ++w) tot += s_red[w];
        const float f_lo = tot - 1.0f;
        float tlo = tau_lo0, tau_m = tau_lo0, fsum = tot;
        for (int it = 0; it < NITER; ++it) {
            dm *= 0.5f;
            tau_m = tlo + dm;
            float t = 0.f;
            for (int i4 = tid; i4 < NV4; i4 += BLOCK) {
                float4 v = x4[i4];
                t += pf(v.x * am1 - tau_m, sq, expo) + pf(v.y * am1 - tau_m, sq, expo)
                   + pf(v.z * am1 - tau_m, sq, expo) + pf(v.w * am1 - tau_m, sq, expo);
            }
            t = wave_sum(t);
            __syncthreads();
            if (lane == 0) s_red[wid] = t;
            __syncthreads();
            float tt = 0.f;
#pragma unroll
            for (int w = 0; w < NWAVE; ++w) tt += s_red[w];
            fsum = tt;
            if ((tt - 1.0f) * f_lo >= 0.0f) tlo = tau_m;
        }
        const float invS = 1.0f / fsum;
        __syncthreads();   // drain zero-fill stores before overwrite
        for (int i4 = tid; i4 < NV4; i4 += BLOCK) {
            float4 v = x4[i4];
            float4 o;
            o.x = pf(v.x * am1 - tau_m, sq, expo) * invS;
            o.y = pf(v.y * am1 - tau_m, sq, expo) * invS;
            o.z = pf(v.z * am1 - tau_m, sq, expo) * invS;
            o.w = pf(v.w * am1 - tau_m, sq, expo) * invS;
            o4[i4] = o;
        }
    }
}

extern "C" void kernel_launch(void* const* d_in, const int* in_sizes, int n_in,
                              void* d_out, int out_size, void* d_ws, size_t ws_size,
                              hipStream_t stream) {
    const float* x       = (const float*)d_in[0];
    const float* alpha_p = (const float*)d_in[1];
    float* out           = (float*)d_out;
    const int rows       = in_sizes[0] / D_DIM;   // 2048
    entmax_bisect_kernel<<<rows, BLOCK, 0, stream>>>(x, alpha_p, out);
}